// Round 19
// baseline (170.145 us; speedup 1.0000x reference)
//
#include <hip/hip_runtime.h>

// Path signature M=4, d=10, L=256, B=2048 — MFMA formulation, round 19.
// = ROUND 18 with ONE change: __launch_bounds__(384,4) (reg cap 128, was 102).
// r18's specialization was poisoned by a scratch spill (VGPR=48, WRITE_SIZE
// +38MB, FETCH +6GB): consumer waves need ~110 regs (64 acc + frags + addr).
// Math identical to r17 (absmax 10.5): b-row eliminated, K-rows per t:
// P=[a_hi,a_lo,r1,r2], Q_cell=[uw,uw,-w/24,-w/12], Q_vcol=[v,v,0,0].
// Waves 0-1 produce (merged pair+cell: w=r1 shared); waves 2-5 pure consumers.
// Slot-major [slot][112][16B], dbuf, 1 barrier/chunk, tail split <8>/<7>.

#define SIG 11110

typedef short bf16x8 __attribute__((ext_vector_type(8)));
typedef float f32x4  __attribute__((ext_vector_type(4)));

__device__ __forceinline__ unsigned cvt_pk2(float lo, float hi) {
    unsigned r;
    asm("v_cvt_pk_bf16_f32 %0, %1, %2" : "=v"(r) : "v"(lo), "v"(hi));
    return r;
}
// (bf16_hi(a) | bf16(a - hi)<<16), hi = truncated-to-bf16 (exact residual)
__device__ __forceinline__ unsigned split_pack(float a) {
    const float hi = __uint_as_float(__float_as_uint(a) & 0xFFFF0000u);
    return cvt_pk2(hi, a - hi);
}

template<int MI, int NI>
__device__ __forceinline__ void consume(const unsigned* __restrict__ Pb,
                                        const unsigned* __restrict__ Qb,
                                        int r0, int c0, int lane,
                                        f32x4 (&acc)[4][4]) {
    const int slot = lane >> 4, rr = lane & 15;
    bf16x8 Bf[NI];
    #pragma unroll
    for (int ni = 0; ni < NI; ++ni)
        Bf[ni] = *(const bf16x8*)(Qb + slot * 448 + (c0 + ni * 16 + rr) * 4);
    #pragma unroll
    for (int mi = 0; mi < MI; ++mi) {
        const bf16x8 Af = *(const bf16x8*)(Pb + slot * 448 + (r0 + mi * 16 + rr) * 4);
        #pragma unroll
        for (int ni = 0; ni < NI; ++ni)
            acc[mi][ni] = __builtin_amdgcn_mfma_f32_16x16x32_bf16(Af, Bf[ni], acc[mi][ni], 0, 0, 0);
    }
}

// NV = valid t's (8 for chunks 0..30, 7 for chunk 31).
template<int NV>
__device__ __forceinline__ void produce_t(int ch, const float* __restrict__ xs,
                                          unsigned* __restrict__ Pb,
                                          unsigned* __restrict__ Qb,
                                          bool isMerged, bool isVcol,
                                          int tid, int i1, int i2,
                                          float x0i, float xL2,
                                          float& c1, float& c2, float& Ds) {
    if (isMerged) {                      // pair (i,j) AND cell (i,j) on one lane
        unsigned p0 = 0, p1 = 0, s0 = 0, s1 = 0;
        #pragma unroll
        for (int tl = 0; tl < 8; ++tl) {
            unsigned pa, pr, pu, pw;
            if (tl < NV) {
                const float n1 = xs[(ch * 8 + tl + 1) * 10 + i1];
                const float n2 = xs[(ch * 8 + tl + 1) * 10 + i2];
                const float vi = n1 - c1, vj = n2 - c2;
                const float s1f = c1 - x0i;
                const float r1  = vi * vj;               // == cell w (shared!)
                const float r2  = s1f * vj;
                const float a   = fmaf(r1, 1.f/6.f, fmaf(r2, 0.5f, Ds));
                pa = split_pack(a);
                pr = cvt_pk2(r1, r2);
                const float m2 = fmaf(-0.5f, c2 + n2, xL2);   // R + v/2 factor
                const float uw = vi * m2;                      // u + w/2
                pu = cvt_pk2(uw, uw);
                pw = cvt_pk2(r1 * (-1.f/24.f), r1 * (-1.f/12.f));
                Ds += fmaf(0.5f, r1, r2);
                c1 = n1; c2 = n2;
            } else { pa = 0u; pr = 0u; pu = 0u; pw = 0u; }
            if ((tl & 1) == 0) { p0 = pa; p1 = pr; s0 = pu; s1 = pw; }
            else {
                *(uint4*)&Pb[(tl >> 1) * 448 + tid * 4] = make_uint4(p0, p1, pa, pr);
                *(uint4*)&Qb[(tl >> 1) * 448 + tid * 4] = make_uint4(s0, s1, pu, pw);
            }
        }
    } else if (isVcol) {                 // Q rows 100..109: v_t (S3 columns)
        unsigned q0 = 0;
        #pragma unroll
        for (int tl = 0; tl < 8; ++tl) {
            unsigned pv;
            if (tl < NV) {
                const float n1 = xs[(ch * 8 + tl + 1) * 10 + i1];
                pv = cvt_pk2(n1 - c1, n1 - c1);
                c1 = n1;
            } else pv = 0u;
            if ((tl & 1) == 0) q0 = pv;
            else *(uint4*)&Qb[(tl >> 1) * 448 + tid * 4] = make_uint4(q0, 0u, pv, 0u);
        }
    }
}

__global__ __launch_bounds__(384, 4)
void sig_mfma12(const float* __restrict__ xg, float* __restrict__ out) {
    __shared__ float    xs[2560];          // path [t*10+dim]           10240 B
    __shared__ unsigned Pl[2][4 * 448];    // dbuf [slot][112 rows][4w] 14336 B
    __shared__ unsigned Ql[2][4 * 448];    //                           14336 B

    const int tid  = threadIdx.x;
    const int b    = blockIdx.x;
    const int lane = tid & 63;
    const int wv   = tid >> 6;             // 0..5
    const float* __restrict__ xb = xg + (size_t)b * 2560;

    // stage path (coalesced) + zero pads (P rows 100..111, Q rows 110..111; both bufs)
    for (int e = tid; e < 2560; e += 384) xs[e] = xb[e];
    {   // 384 P-pad words exactly cover 384 threads
        const int buf = tid / 192, r = tid % 192, slot = r / 48, rem = r % 48;
        Pl[buf][slot * 448 + (100 + rem / 4) * 4 + (rem & 3)] = 0u;
    }
    if (tid < 64) {
        const int buf = tid / 32, r = tid % 32, slot = r / 8, rem = r % 8;
        Ql[buf][slot * 448 + (110 + rem / 4) * 4 + (rem & 3)] = 0u;
    }
    __syncthreads();   // staging visible BEFORE any xs read (r12/r13 lesson)

    // roles: waves 0-1 produce (merged pair+cell tid<100, vcol 100..109);
    //        waves 2-5 pure consumers.
    const bool isMerged = (tid < 100);
    const bool isVcol   = (tid >= 100) && (tid < 110);

    int i1 = 0, i2 = 0;
    if (isMerged)    { i1 = tid / 10;  i2 = tid - i1 * 10; }
    else if (isVcol) { i1 = tid - 100; i2 = i1; }

    float c1 = xs[i1], c2 = xs[i2];             // chains x_t[i1], x_t[i2]
    const float x0i = c1;
    const float xL2 = xs[2550 + i2];            // x_L[j] for the cell u-factor
    float Ds = 0.f;                             // running S2 (exact f32)

    f32x4 acc[4][4];
    #pragma unroll
    for (int mi = 0; mi < 4; ++mi)
        #pragma unroll
        for (int ni = 0; ni < 4; ++ni) acc[mi][ni] = (f32x4){0.f, 0.f, 0.f, 0.f};

    produce_t<8>(0, xs, Pl[0], Ql[0], isMerged, isVcol, tid, i1, i2, x0i, xL2, c1, c2, Ds);
    __syncthreads();

    for (int ch = 0; ch < 32; ++ch) {
        const unsigned* Pb = Pl[ch & 1];
        const unsigned* Qb = Ql[ch & 1];
        if      (wv == 2) consume<4, 4>(Pb, Qb,  0,  0, lane, acc);   // 16
        else if (wv == 3) consume<4, 3>(Pb, Qb,  0, 64, lane, acc);   // 12
        else if (wv == 4) consume<3, 4>(Pb, Qb, 64,  0, lane, acc);   // 12
        else if (wv == 5) consume<3, 3>(Pb, Qb, 64, 64, lane, acc);   //  9
        if (ch < 30)
            produce_t<8>(ch + 1, xs, Pl[(ch + 1) & 1], Ql[(ch + 1) & 1],
                         isMerged, isVcol, tid, i1, i2, x0i, xL2, c1, c2, Ds);
        else if (ch == 30)
            produce_t<7>(31, xs, Pl[1], Ql[1],
                         isMerged, isVcol, tid, i1, i2, x0i, xL2, c1, c2, Ds);
        __syncthreads();   // one barrier/chunk
    }

    // epilogue: [S1(10) | S2(100) | S3(1000) | S4(10000)]
    const size_t base = (size_t)b * SIG;
    if (tid < 10)  out[base + tid] = xs[2550 + tid] - xs[tid];   // S1 exact
    if (isMerged)  out[base + 10 + tid] = Ds;                    // S2 exact

    if (wv >= 2) {
        const int cw = wv - 2;
        const int r0 = (cw < 2) ? 0 : 64;
        const int c0 = (cw & 1) ? 64 : 0;
        #pragma unroll
        for (int mi = 0; mi < 4; ++mi) {
            #pragma unroll
            for (int ni = 0; ni < 4; ++ni) {
                #pragma unroll
                for (int r = 0; r < 4; ++r) {
                    const int m = r0 + mi * 16 + (lane >> 4) * 4 + r;
                    const int n = c0 + ni * 16 + (lane & 15);
                    if (m < 100) {
                        if (n < 100)      out[base + 1110 + m * 100 + n]         = acc[mi][ni][r];
                        else if (n < 110) out[base + 110  + m * 10  + (n - 100)] = acc[mi][ni][r];
                    }
                }
            }
        }
    }
}

extern "C" void kernel_launch(void* const* d_in, const int* in_sizes, int n_in,
                              void* d_out, int out_size, void* d_ws, size_t ws_size,
                              hipStream_t stream) {
    const float* x = (const float*)d_in[0];
    float* out = (float*)d_out;
    const int B = in_sizes[0] / 2560;   // 2048 batches, one block each
    sig_mfma12<<<B, 384, 0, stream>>>(x, out);
}

// Round 20
// 127.168 us; speedup vs baseline: 1.3380x; 1.3380x over previous
//
#include <hip/hip_runtime.h>

// Path signature M=4, d=10, L=256, B=2048 — MFMA formulation, round 20.
// Math identical to r17 (absmax 10.5): b-row eliminated via b=a/2-r1/24-r2/12;
// K-rows per t: P=[a_hi,a_lo,r1,r2], Q_cell=[uw,uw,-w/24,-w/12], Q_vcol=[v,v,0,0].
// Roles = r17 (the 119us best): waves 0-1 pair-scan -> P, waves 2-3 cells/vcols
// -> Q, every wave also consumes a C quadrant (16/12/12/9 tiles).
// ROUND-20: chunk K doubled to 64 (16 t) -> 16 chunks -> 16 barriers (was 32).
// LDS 67.6KB -> 2 blocks/CU (observed co-residency was already ~2.25, so the
// barrier halving is ~free). Consume does the two K=32 halves (slots 0-3, 4-7).
// Slot-major [slot][112][16B], dbuf, staging barrier before chain init.

#define SIG 11110

typedef short bf16x8 __attribute__((ext_vector_type(8)));
typedef float f32x4  __attribute__((ext_vector_type(4)));

__device__ __forceinline__ unsigned cvt_pk2(float lo, float hi) {
    unsigned r;
    asm("v_cvt_pk_bf16_f32 %0, %1, %2" : "=v"(r) : "v"(lo), "v"(hi));
    return r;
}
// (bf16_hi(a) | bf16(a - hi)<<16), hi = truncated-to-bf16 (exact residual)
__device__ __forceinline__ unsigned split_pack(float a) {
    const float hi = __uint_as_float(__float_as_uint(a) & 0xFFFF0000u);
    return cvt_pk2(hi, a - hi);
}

template<int MI, int NI>
__device__ __forceinline__ void consume(const unsigned* __restrict__ Pb,
                                        const unsigned* __restrict__ Qb,
                                        int r0, int c0, int lane,
                                        f32x4 (&acc)[4][4]) {
    const int slot = lane >> 4, rr = lane & 15;
    bf16x8 Bf[NI];
    #pragma unroll
    for (int ni = 0; ni < NI; ++ni)
        Bf[ni] = *(const bf16x8*)(Qb + slot * 448 + (c0 + ni * 16 + rr) * 4);
    #pragma unroll
    for (int mi = 0; mi < MI; ++mi) {
        const bf16x8 Af = *(const bf16x8*)(Pb + slot * 448 + (r0 + mi * 16 + rr) * 4);
        #pragma unroll
        for (int ni = 0; ni < NI; ++ni)
            acc[mi][ni] = __builtin_amdgcn_mfma_f32_16x16x32_bf16(Af, Bf[ni], acc[mi][ni], 0, 0, 0);
    }
}

// NV = valid t's in this chunk (16 for chunks 0..14, 15 for chunk 15).
template<int NV>
__device__ __forceinline__ void produce_t(int ch, const float* __restrict__ xs,
                                          unsigned* __restrict__ Pb,
                                          unsigned* __restrict__ Qb,
                                          bool isPair, bool isCell, bool isVcol,
                                          int tid, int qrow, int i1, int i2,
                                          float x0i, float xL2,
                                          float& c1, float& c2, float& Ds) {
    if (isPair) {
        unsigned q0 = 0, q1 = 0;
        #pragma unroll
        for (int tl = 0; tl < 16; ++tl) {
            unsigned pa, pr;
            if (tl < NV) {
                const float n1 = xs[(ch * 16 + tl + 1) * 10 + i1];
                const float n2 = xs[(ch * 16 + tl + 1) * 10 + i2];
                const float vi = n1 - c1, vj = n2 - c2;
                const float s1f = c1 - x0i;
                const float r1  = vi * vj;
                const float r2  = s1f * vj;
                const float a   = fmaf(r1, 1.f/6.f, fmaf(r2, 0.5f, Ds));
                pa = split_pack(a);
                pr = cvt_pk2(r1, r2);
                Ds += fmaf(0.5f, r1, r2);
                c1 = n1; c2 = n2;
            } else { pa = 0u; pr = 0u; }
            if ((tl & 1) == 0) { q0 = pa; q1 = pr; }
            else *(uint4*)&Pb[(tl >> 1) * 448 + tid * 4] = make_uint4(q0, q1, pa, pr);
        }
    } else if (isCell) {
        unsigned q0 = 0, q1 = 0;
        #pragma unroll
        for (int tl = 0; tl < 16; ++tl) {
            unsigned pu, pw;
            if (tl < NV) {
                const float n1 = xs[(ch * 16 + tl + 1) * 10 + i1];
                const float n2 = xs[(ch * 16 + tl + 1) * 10 + i2];
                const float vk = n1 - c1, vl = n2 - c2;
                const float w  = vk * vl;
                const float m2 = fmaf(-0.5f, c2 + n2, xL2);   // R + v/2 factor
                const float uw = vk * m2;                     // u + w/2
                pu = cvt_pk2(uw, uw);
                pw = cvt_pk2(w * (-1.f/24.f), w * (-1.f/12.f));
                c1 = n1; c2 = n2;
            } else { pu = 0u; pw = 0u; }
            if ((tl & 1) == 0) { q0 = pu; q1 = pw; }
            else *(uint4*)&Qb[(tl >> 1) * 448 + qrow * 4] = make_uint4(q0, q1, pu, pw);
        }
    } else if (isVcol) {
        unsigned q0 = 0;
        #pragma unroll
        for (int tl = 0; tl < 16; ++tl) {
            unsigned pv;
            if (tl < NV) {
                const float n1 = xs[(ch * 16 + tl + 1) * 10 + i1];
                pv = cvt_pk2(n1 - c1, n1 - c1);
                c1 = n1;
            } else pv = 0u;
            if ((tl & 1) == 0) q0 = pv;
            else *(uint4*)&Qb[(tl >> 1) * 448 + qrow * 4] = make_uint4(q0, 0u, pv, 0u);
        }
    }
}

__global__ __launch_bounds__(256, 3)
void sig_mfma13(const float* __restrict__ xg, float* __restrict__ out) {
    __shared__ float    xs[2560];          // path [t*10+dim]            10240 B
    __shared__ unsigned Pl[2][8 * 448];    // dbuf [slot0..7][112][4w]   28672 B
    __shared__ unsigned Ql[2][8 * 448];    //                            28672 B

    const int tid  = threadIdx.x;
    const int b    = blockIdx.x;
    const int lane = tid & 63;
    const int wv   = tid >> 6;
    const float* __restrict__ xb = xg + (size_t)b * 2560;

    // stage path (coalesced) + zero pads (P rows 100..111, Q rows 110..111; both bufs)
    #pragma unroll
    for (int r = 0; r < 10; ++r) xs[r * 256 + tid] = xb[r * 256 + tid];
    for (int e = tid; e < 768; e += 256) {
        const int buf = e / 384, r = e % 384, slot = r / 48, rem = r % 48;
        Pl[buf][slot * 448 + (100 + rem / 4) * 4 + (rem & 3)] = 0u;
    }
    if (tid < 128) {
        const int buf = tid / 64, r = tid % 64, slot = r / 8, rem = r % 8;
        Ql[buf][slot * 448 + (110 + rem / 4) * 4 + (rem & 3)] = 0u;
    }
    __syncthreads();   // staging visible BEFORE any xs read (r12/r13 lesson)

    // roles: waves 0-1 = pair scan -> P ; waves 2-3 = closed-form -> Q
    const bool isPair = (tid < 100);
    const int  qrow   = tid - 128;
    const bool isCell = (qrow >= 0) && (qrow < 100);
    const bool isVcol = (qrow >= 100) && (qrow < 110);

    int i1 = 0, i2 = 0;
    if (isPair)      { i1 = tid / 10;  i2 = tid - i1 * 10; }
    else if (isCell) { i1 = qrow / 10; i2 = qrow - i1 * 10; }
    else if (isVcol) { i1 = qrow - 100; i2 = i1; }

    float c1 = xs[i1], c2 = xs[i2];             // chains x_t[i1], x_t[i2]
    const float x0i = c1;
    const float xL2 = xs[2550 + i2];            // cells: x_L[l]
    float Ds = 0.f;                             // pairs: running S2 (exact f32)

    f32x4 acc[4][4];
    #pragma unroll
    for (int mi = 0; mi < 4; ++mi)
        #pragma unroll
        for (int ni = 0; ni < 4; ++ni) acc[mi][ni] = (f32x4){0.f, 0.f, 0.f, 0.f};

    produce_t<16>(0, xs, Pl[0], Ql[0], isPair, isCell, isVcol,
                  tid, qrow, i1, i2, x0i, xL2, c1, c2, Ds);
    __syncthreads();

    for (int ch = 0; ch < 16; ++ch) {
        const unsigned* Pb = Pl[ch & 1];
        const unsigned* Qb = Ql[ch & 1];
        // two K=32 halves of the K=64 chunk (slots 0-3, then 4-7)
        if      (wv == 0) { consume<4, 4>(Pb, Qb,  0,  0, lane, acc);
                            consume<4, 4>(Pb + 1792, Qb + 1792,  0,  0, lane, acc); }
        else if (wv == 1) { consume<4, 3>(Pb, Qb,  0, 64, lane, acc);
                            consume<4, 3>(Pb + 1792, Qb + 1792,  0, 64, lane, acc); }
        else if (wv == 2) { consume<3, 4>(Pb, Qb, 64,  0, lane, acc);
                            consume<3, 4>(Pb + 1792, Qb + 1792, 64,  0, lane, acc); }
        else              { consume<3, 3>(Pb, Qb, 64, 64, lane, acc);
                            consume<3, 3>(Pb + 1792, Qb + 1792, 64, 64, lane, acc); }
        if (ch < 14)
            produce_t<16>(ch + 1, xs, Pl[(ch + 1) & 1], Ql[(ch + 1) & 1],
                          isPair, isCell, isVcol, tid, qrow, i1, i2, x0i, xL2, c1, c2, Ds);
        else if (ch == 14)
            produce_t<15>(15, xs, Pl[1], Ql[1],
                          isPair, isCell, isVcol, tid, qrow, i1, i2, x0i, xL2, c1, c2, Ds);
        __syncthreads();   // ONE barrier per K=64 chunk (16 total, was 32)
    }

    // epilogue: [S1(10) | S2(100) | S3(1000) | S4(10000)]
    const size_t base = (size_t)b * SIG;
    if (tid < 10)  out[base + tid] = xs[2550 + tid] - xs[tid];   // S1 exact
    if (isPair)    out[base + 10 + tid] = Ds;                    // S2 exact

    const int r0 = (wv < 2) ? 0 : 64;
    const int c0 = (wv == 0 || wv == 2) ? 0 : 64;
    #pragma unroll
    for (int mi = 0; mi < 4; ++mi) {
        #pragma unroll
        for (int ni = 0; ni < 4; ++ni) {
            #pragma unroll
            for (int r = 0; r < 4; ++r) {
                const int m = r0 + mi * 16 + (lane >> 4) * 4 + r;
                const int n = c0 + ni * 16 + (lane & 15);
                if (m < 100) {
                    if (n < 100)      out[base + 1110 + m * 100 + n]         = acc[mi][ni][r];
                    else if (n < 110) out[base + 110  + m * 10  + (n - 100)] = acc[mi][ni][r];
                }
            }
        }
    }
}

extern "C" void kernel_launch(void* const* d_in, const int* in_sizes, int n_in,
                              void* d_out, int out_size, void* d_ws, size_t ws_size,
                              hipStream_t stream) {
    const float* x = (const float*)d_in[0];
    float* out = (float*)d_out;
    const int B = in_sizes[0] / 2560;   // 2048 batches, one block each
    sig_mfma13<<<B, 256, 0, stream>>>(x, out);
}

// Round 21
// 91.785 us; speedup vs baseline: 1.8537x; 1.3855x over previous
//
#include <hip/hip_runtime.h>

// Path signature M=4, d=10, L=256, B=2048 — MFMA formulation, round 21.
// Math identical to r17 (absmax 10.5): b-row eliminated via b=a/2-r1/24-r2/12;
// K-rows per t: P=[a_hi,a_lo,r1,r2], Q_cell=[uw,uw,-w/24,-w/12], Q_vcol=[v,v,0,0].
// ROUND-21: occupancy attack. r17 allocs acc[4][4]=64 AGPR in EVERY wave (runtime
// quadrant switch) -> 140 regs/wave -> 3 waves/SIMD. Now the chunk loop is
// templated PER WAVE with exactly-sized acc (tile partition 12/13/12/12, max 52):
//   w0: rows0-63 x cols0-47 (4x3) | w1: rows64-111 x cols0-47 (3x3) + rows0-63 x
//   cols96-111 (4x1) | w2: rows0-63 x cols48-95 (4x3) | w3: rows64-111 x cols48-111 (3x4)
// ~76 arch + 52 acc = 128 -> 4 waves/SIMD; LDS 38.9KB -> 4 blocks/CU.
// launch_bounds(256,4) cap=128 (r19 precedent: 124 under cap 128, no spill).
// Wave-specialized loops each execute 33 barriers -> counts match (legal).

#define SIG 11110

typedef short bf16x8 __attribute__((ext_vector_type(8)));
typedef float f32x4  __attribute__((ext_vector_type(4)));

__device__ __forceinline__ unsigned cvt_pk2(float lo, float hi) {
    unsigned r;
    asm("v_cvt_pk_bf16_f32 %0, %1, %2" : "=v"(r) : "v"(lo), "v"(hi));
    return r;
}
// (bf16_hi(a) | bf16(a - hi)<<16), hi = truncated-to-bf16 (exact residual)
__device__ __forceinline__ unsigned split_pack(float a) {
    const float hi = __uint_as_float(__float_as_uint(a) & 0xFFFF0000u);
    return cvt_pk2(hi, a - hi);
}

template<int MI, int NI>
__device__ __forceinline__ void consume(const unsigned* __restrict__ Pb,
                                        const unsigned* __restrict__ Qb,
                                        int r0, int c0, int lane,
                                        f32x4 (&acc)[MI][NI]) {
    const int slot = lane >> 4, rr = lane & 15;
    bf16x8 Bf[NI];
    #pragma unroll
    for (int ni = 0; ni < NI; ++ni)
        Bf[ni] = *(const bf16x8*)(Qb + slot * 448 + (c0 + ni * 16 + rr) * 4);
    #pragma unroll
    for (int mi = 0; mi < MI; ++mi) {
        const bf16x8 Af = *(const bf16x8*)(Pb + slot * 448 + (r0 + mi * 16 + rr) * 4);
        #pragma unroll
        for (int ni = 0; ni < NI; ++ni)
            acc[mi][ni] = __builtin_amdgcn_mfma_f32_16x16x32_bf16(Af, Bf[ni], acc[mi][ni], 0, 0, 0);
    }
}

template<int MI, int NI>
__device__ __forceinline__ void write_seg(int r0, int c0, int lane,
                                          const f32x4 (&acc)[MI][NI],
                                          float* __restrict__ out, size_t base) {
    #pragma unroll
    for (int mi = 0; mi < MI; ++mi) {
        #pragma unroll
        for (int ni = 0; ni < NI; ++ni) {
            #pragma unroll
            for (int r = 0; r < 4; ++r) {
                const int m = r0 + mi * 16 + (lane >> 4) * 4 + r;
                const int n = c0 + ni * 16 + (lane & 15);
                if (m < 100) {
                    if (n < 100)      out[base + 1110 + m * 100 + n]         = acc[mi][ni][r];
                    else if (n < 110) out[base + 110  + m * 10  + (n - 100)] = acc[mi][ni][r];
                }
            }
        }
    }
}

// NV = valid t's in this chunk (8 for chunks 0..30, 7 for chunk 31).
template<int NV>
__device__ __forceinline__ void produce_t(int ch, const float* __restrict__ xs,
                                          unsigned* __restrict__ Pb,
                                          unsigned* __restrict__ Qb,
                                          bool isPair, bool isCell, bool isVcol,
                                          int tid, int qrow, int i1, int i2,
                                          float x0i, float xL2,
                                          float& c1, float& c2, float& Ds) {
    if (isPair) {
        unsigned q0 = 0, q1 = 0;
        #pragma unroll
        for (int tl = 0; tl < 8; ++tl) {
            unsigned pa, pr;
            if (tl < NV) {
                const float n1 = xs[(ch * 8 + tl + 1) * 10 + i1];
                const float n2 = xs[(ch * 8 + tl + 1) * 10 + i2];
                const float vi = n1 - c1, vj = n2 - c2;
                const float s1f = c1 - x0i;
                const float r1  = vi * vj;
                const float r2  = s1f * vj;
                const float a   = fmaf(r1, 1.f/6.f, fmaf(r2, 0.5f, Ds));
                pa = split_pack(a);
                pr = cvt_pk2(r1, r2);
                Ds += fmaf(0.5f, r1, r2);
                c1 = n1; c2 = n2;
            } else { pa = 0u; pr = 0u; }
            if ((tl & 1) == 0) { q0 = pa; q1 = pr; }
            else *(uint4*)&Pb[(tl >> 1) * 448 + tid * 4] = make_uint4(q0, q1, pa, pr);
        }
    } else if (isCell) {
        unsigned q0 = 0, q1 = 0;
        #pragma unroll
        for (int tl = 0; tl < 8; ++tl) {
            unsigned pu, pw;
            if (tl < NV) {
                const float n1 = xs[(ch * 8 + tl + 1) * 10 + i1];
                const float n2 = xs[(ch * 8 + tl + 1) * 10 + i2];
                const float vk = n1 - c1, vl = n2 - c2;
                const float w  = vk * vl;
                const float m2 = fmaf(-0.5f, c2 + n2, xL2);   // R + v/2 factor
                const float uw = vk * m2;                     // u + w/2
                pu = cvt_pk2(uw, uw);
                pw = cvt_pk2(w * (-1.f/24.f), w * (-1.f/12.f));
                c1 = n1; c2 = n2;
            } else { pu = 0u; pw = 0u; }
            if ((tl & 1) == 0) { q0 = pu; q1 = pw; }
            else *(uint4*)&Qb[(tl >> 1) * 448 + qrow * 4] = make_uint4(q0, q1, pu, pw);
        }
    } else if (isVcol) {
        unsigned q0 = 0;
        #pragma unroll
        for (int tl = 0; tl < 8; ++tl) {
            unsigned pv;
            if (tl < NV) {
                const float n1 = xs[(ch * 8 + tl + 1) * 10 + i1];
                pv = cvt_pk2(n1 - c1, n1 - c1);
                c1 = n1;
            } else pv = 0u;
            if ((tl & 1) == 0) q0 = pv;
            else *(uint4*)&Qb[(tl >> 1) * 448 + qrow * 4] = make_uint4(q0, 0u, pv, 0u);
        }
    }
}

// Whole chunk-loop per wave: exactly-sized accumulators. B segment optional (MIB=0).
template<int MIA, int NIA, int R0A, int C0A, int MIB, int NIB, int R0B, int C0B>
__device__ __forceinline__ void run_wave(const float* __restrict__ xs,
                                         unsigned (&Pl)[2][1792],
                                         unsigned (&Ql)[2][1792],
                                         bool isPair, bool isCell, bool isVcol,
                                         int tid, int qrow, int i1, int i2,
                                         float x0i, float xL2, float c1, float c2,
                                         int lane, float* __restrict__ out, size_t base) {
    float Ds = 0.f;
    f32x4 accA[MIA][NIA];
    #pragma unroll
    for (int mi = 0; mi < MIA; ++mi)
        #pragma unroll
        for (int ni = 0; ni < NIA; ++ni) accA[mi][ni] = (f32x4){0.f, 0.f, 0.f, 0.f};
    constexpr int MB = (MIB > 0) ? MIB : 1;
    constexpr int NB = (NIB > 0) ? NIB : 1;
    f32x4 accB[MB][NB];
    if constexpr (MIB > 0) {
        #pragma unroll
        for (int mi = 0; mi < MB; ++mi)
            #pragma unroll
            for (int ni = 0; ni < NB; ++ni) accB[mi][ni] = (f32x4){0.f, 0.f, 0.f, 0.f};
    }

    produce_t<8>(0, xs, Pl[0], Ql[0], isPair, isCell, isVcol,
                 tid, qrow, i1, i2, x0i, xL2, c1, c2, Ds);
    __syncthreads();

    for (int ch = 0; ch < 32; ++ch) {
        const unsigned* Pb = Pl[ch & 1];
        const unsigned* Qb = Ql[ch & 1];
        consume<MIA, NIA>(Pb, Qb, R0A, C0A, lane, accA);
        if constexpr (MIB > 0) consume<MIB, NIB>(Pb, Qb, R0B, C0B, lane, accB);
        if (ch < 30)
            produce_t<8>(ch + 1, xs, Pl[(ch + 1) & 1], Ql[(ch + 1) & 1],
                         isPair, isCell, isVcol, tid, qrow, i1, i2, x0i, xL2, c1, c2, Ds);
        else if (ch == 30)
            produce_t<7>(31, xs, Pl[1], Ql[1],
                         isPair, isCell, isVcol, tid, qrow, i1, i2, x0i, xL2, c1, c2, Ds);
        __syncthreads();   // 33 barriers in every instantiation — counts match
    }

    if (isPair) out[base + 10 + tid] = Ds;          // S2 exact
    write_seg<MIA, NIA>(R0A, C0A, lane, accA, out, base);
    if constexpr (MIB > 0) write_seg<MIB, NIB>(R0B, C0B, lane, accB, out, base);
}

__global__ __launch_bounds__(256, 4)
void sig_mfma14(const float* __restrict__ xg, float* __restrict__ out) {
    __shared__ float    xs[2560];          // path [t*10+dim]           10240 B
    __shared__ unsigned Pl[2][1792];       // dbuf [slot][112 rows][4w] 14336 B
    __shared__ unsigned Ql[2][1792];       //                           14336 B

    const int tid  = threadIdx.x;
    const int b    = blockIdx.x;
    const int lane = tid & 63;
    const int wv   = tid >> 6;
    const float* __restrict__ xb = xg + (size_t)b * 2560;

    // stage path (coalesced) + zero pads (P rows 100..111, Q rows 110..111; both bufs)
    #pragma unroll
    for (int r = 0; r < 10; ++r) xs[r * 256 + tid] = xb[r * 256 + tid];
    for (int e = tid; e < 384; e += 256) {
        const int buf = e / 192, r = e % 192, slot = r / 48, rem = r % 48;
        Pl[buf][slot * 448 + (100 + rem / 4) * 4 + (rem & 3)] = 0u;
    }
    if (tid < 64) {
        const int buf = tid / 32, r = tid % 32, slot = r / 8, rem = r % 8;
        Ql[buf][slot * 448 + (110 + rem / 4) * 4 + (rem & 3)] = 0u;
    }
    __syncthreads();   // staging visible BEFORE any xs read (r12/r13 lesson)

    // roles: waves 0-1 = pair scan -> P ; waves 2-3 = closed-form -> Q
    const bool isPair = (tid < 100);
    const int  qrow   = tid - 128;
    const bool isCell = (qrow >= 0) && (qrow < 100);
    const bool isVcol = (qrow >= 100) && (qrow < 110);

    int i1 = 0, i2 = 0;
    if (isPair)      { i1 = tid / 10;  i2 = tid - i1 * 10; }
    else if (isCell) { i1 = qrow / 10; i2 = qrow - i1 * 10; }
    else if (isVcol) { i1 = qrow - 100; i2 = i1; }

    const float c1 = xs[i1], c2 = xs[i2];       // chains x_t[i1], x_t[i2]
    const float x0i = c1;
    const float xL2 = xs[2550 + i2];            // cells: x_L[l]
    const size_t base = (size_t)b * SIG;

    // tile partition (12/13/12/12, max 52 acc regs):
    //   w0: rows 0-63   x cols 0-47   (4x3)
    //   w1: rows 64-111 x cols 0-47   (3x3) + rows 0-63 x cols 96-111 (4x1)
    //   w2: rows 0-63   x cols 48-95  (4x3)
    //   w3: rows 64-111 x cols 48-111 (3x4)
    if      (wv == 0) run_wave<4, 3,  0,  0, 0, 0, 0,  0>(xs, Pl, Ql, isPair, isCell, isVcol,
                          tid, qrow, i1, i2, x0i, xL2, c1, c2, lane, out, base);
    else if (wv == 1) run_wave<3, 3, 64,  0, 4, 1, 0, 96>(xs, Pl, Ql, isPair, isCell, isVcol,
                          tid, qrow, i1, i2, x0i, xL2, c1, c2, lane, out, base);
    else if (wv == 2) run_wave<4, 3,  0, 48, 0, 0, 0,  0>(xs, Pl, Ql, isPair, isCell, isVcol,
                          tid, qrow, i1, i2, x0i, xL2, c1, c2, lane, out, base);
    else              run_wave<3, 4, 64, 48, 0, 0, 0,  0>(xs, Pl, Ql, isPair, isCell, isVcol,
                          tid, qrow, i1, i2, x0i, xL2, c1, c2, lane, out, base);

    if (tid < 10) out[base + tid] = xs[2550 + tid] - xs[tid];   // S1 exact
}

extern "C" void kernel_launch(void* const* d_in, const int* in_sizes, int n_in,
                              void* d_out, int out_size, void* d_ws, size_t ws_size,
                              hipStream_t stream) {
    const float* x = (const float*)d_in[0];
    float* out = (float*)d_out;
    const int B = in_sizes[0] / 2560;   // 2048 batches, one block each
    sig_mfma14<<<B, 256, 0, stream>>>(x, out);
}

// Round 22
// 86.197 us; speedup vs baseline: 1.9739x; 1.0648x over previous
//
#include <hip/hip_runtime.h>

// Path signature M=4, d=10, L=256, B=2048 — MFMA formulation, round 22.
// Math identical to r17/r21 (absmax 10.5): b-row eliminated; per-t K-rows:
// P=[a_hi,a_lo,r1,r2], Q_cell=[uw,uw,-w/24,-w/12], Q_vcol=[v,v,0,0], where
// a=r1/6+r2/2+S2, r1=vi*vj, r2=S1_i*vj, uw=vk*(R+v/2), w=vk*vl.
// ROUND-22: increments staged TRANSPOSED vt[dim][t] (stride 260: 16B-aligned,
// 4-bank stagger) -> producer chain reads are 2x float4 ds_read per dim per
// chunk (was 16 scalar ds_reads); s1f/Rv carried incrementally (xs deleted);
// vt[*][255]=0 makes t=255 contribute exactly zero -> NO tail template, 32
// uniform chunks. Roles swapped: cell waves (lighter) take the 13-tile max.
// Partition 12/13/12/12 (max 52 acc regs), launch_bounds(256,4) cap 128.

#define SIG 11110

typedef short bf16x8 __attribute__((ext_vector_type(8)));
typedef float f32x4  __attribute__((ext_vector_type(4)));

__device__ __forceinline__ unsigned cvt_pk2(float lo, float hi) {
    unsigned r;
    asm("v_cvt_pk_bf16_f32 %0, %1, %2" : "=v"(r) : "v"(lo), "v"(hi));
    return r;
}
// (bf16_hi(a) | bf16(a - hi)<<16), hi = truncated-to-bf16 (exact residual)
__device__ __forceinline__ unsigned split_pack(float a) {
    const float hi = __uint_as_float(__float_as_uint(a) & 0xFFFF0000u);
    return cvt_pk2(hi, a - hi);
}

template<int MI, int NI>
__device__ __forceinline__ void consume(const unsigned* __restrict__ Pb,
                                        const unsigned* __restrict__ Qb,
                                        int r0, int c0, int lane,
                                        f32x4 (&acc)[MI][NI]) {
    const int slot = lane >> 4, rr = lane & 15;
    bf16x8 Bf[NI];
    #pragma unroll
    for (int ni = 0; ni < NI; ++ni)
        Bf[ni] = *(const bf16x8*)(Qb + slot * 448 + (c0 + ni * 16 + rr) * 4);
    #pragma unroll
    for (int mi = 0; mi < MI; ++mi) {
        const bf16x8 Af = *(const bf16x8*)(Pb + slot * 448 + (r0 + mi * 16 + rr) * 4);
        #pragma unroll
        for (int ni = 0; ni < NI; ++ni)
            acc[mi][ni] = __builtin_amdgcn_mfma_f32_16x16x32_bf16(Af, Bf[ni], acc[mi][ni], 0, 0, 0);
    }
}

template<int MI, int NI>
__device__ __forceinline__ void write_seg(int r0, int c0, int lane,
                                          const f32x4 (&acc)[MI][NI],
                                          float* __restrict__ out, size_t base) {
    #pragma unroll
    for (int mi = 0; mi < MI; ++mi) {
        #pragma unroll
        for (int ni = 0; ni < NI; ++ni) {
            #pragma unroll
            for (int r = 0; r < 4; ++r) {
                const int m = r0 + mi * 16 + (lane >> 4) * 4 + r;
                const int n = c0 + ni * 16 + (lane & 15);
                if (m < 100) {
                    if (n < 100)      out[base + 1110 + m * 100 + n]         = acc[mi][ni][r];
                    else if (n < 110) out[base + 110  + m * 10  + (n - 100)] = acc[mi][ni][r];
                }
            }
        }
    }
}

__device__ __forceinline__ void produce(int ch, const float* __restrict__ vt,
                                        unsigned* __restrict__ Pb,
                                        unsigned* __restrict__ Qb,
                                        bool isPair, bool isCell, bool isVcol,
                                        int prow, int qrow, int i1, int i2,
                                        float& s1f, float& Rv, float& Ds) {
    if (isPair) {
        const float4 a0 = *(const float4*)(vt + i1 * 260 + ch * 8);
        const float4 a1 = *(const float4*)(vt + i1 * 260 + ch * 8 + 4);
        const float4 b0 = *(const float4*)(vt + i2 * 260 + ch * 8);
        const float4 b1 = *(const float4*)(vt + i2 * 260 + ch * 8 + 4);
        const float v1[8] = {a0.x,a0.y,a0.z,a0.w,a1.x,a1.y,a1.z,a1.w};
        const float v2[8] = {b0.x,b0.y,b0.z,b0.w,b1.x,b1.y,b1.z,b1.w};
        unsigned q0 = 0, q1 = 0;
        #pragma unroll
        for (int tl = 0; tl < 8; ++tl) {
            const float vi = v1[tl], vj = v2[tl];
            const float r1 = vi * vj;
            const float r2 = s1f * vj;
            const float a  = fmaf(r1, 1.f/6.f, fmaf(r2, 0.5f, Ds));
            const unsigned pa = split_pack(a), pr = cvt_pk2(r1, r2);
            Ds += fmaf(0.5f, r1, r2);
            s1f += vi;
            if ((tl & 1) == 0) { q0 = pa; q1 = pr; }
            else *(uint4*)&Pb[(tl >> 1) * 448 + prow * 4] = make_uint4(q0, q1, pa, pr);
        }
    } else if (isCell) {
        const float4 a0 = *(const float4*)(vt + i1 * 260 + ch * 8);
        const float4 a1 = *(const float4*)(vt + i1 * 260 + ch * 8 + 4);
        const float4 b0 = *(const float4*)(vt + i2 * 260 + ch * 8);
        const float4 b1 = *(const float4*)(vt + i2 * 260 + ch * 8 + 4);
        const float v1[8] = {a0.x,a0.y,a0.z,a0.w,a1.x,a1.y,a1.z,a1.w};
        const float v2[8] = {b0.x,b0.y,b0.z,b0.w,b1.x,b1.y,b1.z,b1.w};
        unsigned q0 = 0, q1 = 0;
        #pragma unroll
        for (int tl = 0; tl < 8; ++tl) {
            const float vk = v1[tl], vl = v2[tl];
            const float w  = vk * vl;
            const float m2 = fmaf(-0.5f, vl, Rv);   // xL - (x_t+x_{t+1})/2
            Rv -= vl;
            const float uw = vk * m2;               // u + w/2
            const unsigned pu = cvt_pk2(uw, uw);
            const unsigned pw = cvt_pk2(w * (-1.f/24.f), w * (-1.f/12.f));
            if ((tl & 1) == 0) { q0 = pu; q1 = pw; }
            else *(uint4*)&Qb[(tl >> 1) * 448 + qrow * 4] = make_uint4(q0, q1, pu, pw);
        }
    } else if (isVcol) {
        const float4 a0 = *(const float4*)(vt + i1 * 260 + ch * 8);
        const float4 a1 = *(const float4*)(vt + i1 * 260 + ch * 8 + 4);
        const float v1[8] = {a0.x,a0.y,a0.z,a0.w,a1.x,a1.y,a1.z,a1.w};
        unsigned q0 = 0;
        #pragma unroll
        for (int tl = 0; tl < 8; ++tl) {
            const unsigned pv = cvt_pk2(v1[tl], v1[tl]);
            if ((tl & 1) == 0) q0 = pv;
            else *(uint4*)&Qb[(tl >> 1) * 448 + qrow * 4] = make_uint4(q0, 0u, pv, 0u);
        }
    }
}

// Whole chunk-loop per wave: exactly-sized accumulators. B segment optional (MIB=0).
template<int MIA, int NIA, int R0A, int C0A, int MIB, int NIB, int R0B, int C0B>
__device__ __forceinline__ void run_wave(const float* __restrict__ vt,
                                         unsigned (&Pl)[2][1792],
                                         unsigned (&Ql)[2][1792],
                                         bool isPair, bool isCell, bool isVcol,
                                         int prow, int qrow, int i1, int i2,
                                         float s1f, float Rv,
                                         int lane, float* __restrict__ out, size_t base) {
    float Ds = 0.f;
    f32x4 accA[MIA][NIA];
    #pragma unroll
    for (int mi = 0; mi < MIA; ++mi)
        #pragma unroll
        for (int ni = 0; ni < NIA; ++ni) accA[mi][ni] = (f32x4){0.f, 0.f, 0.f, 0.f};
    constexpr int MB = (MIB > 0) ? MIB : 1;
    constexpr int NB = (NIB > 0) ? NIB : 1;
    f32x4 accB[MB][NB];
    if constexpr (MIB > 0) {
        #pragma unroll
        for (int mi = 0; mi < MB; ++mi)
            #pragma unroll
            for (int ni = 0; ni < NB; ++ni) accB[mi][ni] = (f32x4){0.f, 0.f, 0.f, 0.f};
    }

    produce(0, vt, Pl[0], Ql[0], isPair, isCell, isVcol, prow, qrow, i1, i2, s1f, Rv, Ds);
    __syncthreads();

    for (int ch = 0; ch < 32; ++ch) {
        const unsigned* Pb = Pl[ch & 1];
        const unsigned* Qb = Ql[ch & 1];
        consume<MIA, NIA>(Pb, Qb, R0A, C0A, lane, accA);
        if constexpr (MIB > 0) consume<MIB, NIB>(Pb, Qb, R0B, C0B, lane, accB);
        if (ch < 31)
            produce(ch + 1, vt, Pl[(ch + 1) & 1], Ql[(ch + 1) & 1],
                    isPair, isCell, isVcol, prow, qrow, i1, i2, s1f, Rv, Ds);
        __syncthreads();   // 33 barriers in every instantiation — counts match
    }

    if (isPair) out[base + 10 + prow] = Ds;          // S2 exact
    write_seg<MIA, NIA>(R0A, C0A, lane, accA, out, base);
    if constexpr (MIB > 0) write_seg<MIB, NIB>(R0B, C0B, lane, accB, out, base);
}

__global__ __launch_bounds__(256, 4)
void sig_mfma15(const float* __restrict__ xg, float* __restrict__ out) {
    __shared__ float    vt[2600];          // increments [dim][260] (t pad)  10400 B
    __shared__ unsigned Pl[2][1792];       // dbuf [slot][112 rows][4w]      14336 B
    __shared__ unsigned Ql[2][1792];       //                                14336 B

    const int tid  = threadIdx.x;
    const int b    = blockIdx.x;
    const int lane = tid & 63;
    const int wv   = tid >> 6;
    const float* __restrict__ xb = xg + (size_t)b * 2560;

    // stage increments transposed (coalesced global reads, L1 absorbs the x2)
    for (int e = tid; e < 2550; e += 256) {
        const int t = e / 10, d = e - t * 10;
        vt[d * 260 + t] = xb[e + 10] - xb[e];
    }
    if (tid < 10) vt[tid * 260 + 255] = 0.f;    // t=255 contributes exactly 0
    // zero pads: P rows 100..111, Q rows 110..111 (both bufs)
    for (int e = tid; e < 384; e += 256) {
        const int buf = e / 192, r = e % 192, slot = r / 48, rem = r % 48;
        Pl[buf][slot * 448 + (100 + rem / 4) * 4 + (rem & 3)] = 0u;
    }
    if (tid < 64) {
        const int buf = tid / 32, r = tid % 32, slot = r / 8, rem = r % 8;
        Ql[buf][slot * 448 + (110 + rem / 4) * 4 + (rem & 3)] = 0u;
    }
    __syncthreads();   // staging visible BEFORE produce(0) (r12/r13 lesson)

    // roles: waves 0-1 = cells/vcols -> Q ; waves 2-3 = pair scan -> P
    const int  pid    = tid - 128;
    const bool isPair = (pid >= 0) && (pid < 100);
    const bool isCell = (tid < 100);
    const bool isVcol = (tid >= 100) && (tid < 110);
    const int  prow   = isPair ? pid : 0;
    const int  qrow   = tid;                     // cell rows 0..99, vcol 100..109

    int i1 = 0, i2 = 0;
    if (isPair)      { i1 = pid / 10; i2 = pid - i1 * 10; }
    else if (isCell) { i1 = tid / 10; i2 = tid - i1 * 10; }
    else if (isVcol) { i1 = tid - 100; i2 = i1; }

    const float s1f = 0.f;
    const float Rv  = isCell ? (xb[2550 + i2] - xb[i2]) : 0.f;  // xL - x0 (suffix init)
    const size_t base = (size_t)b * SIG;

    // tile partition 12/13/12/12 (max 52 acc regs); cell waves take the 13:
    //   w0 (cell): rows0-63 x cols48-95            (4x3 = 12)
    //   w1 (cell): rows64-111 x cols48-95 (3x3) + rows0-63 x cols96-111 (4x1) = 13
    //   w2 (pair): rows0-63 x cols0-47             (4x3 = 12)
    //   w3 (pair): rows64-111 x cols0-47 (3x3) + rows64-111 x cols96-111 (3x1) = 12
    if      (wv == 0) run_wave<4, 3,  0, 48, 0, 0,  0,  0>(vt, Pl, Ql, isPair, isCell, isVcol,
                          prow, qrow, i1, i2, s1f, Rv, lane, out, base);
    else if (wv == 1) run_wave<3, 3, 64, 48, 4, 1,  0, 96>(vt, Pl, Ql, isPair, isCell, isVcol,
                          prow, qrow, i1, i2, s1f, Rv, lane, out, base);
    else if (wv == 2) run_wave<4, 3,  0,  0, 0, 0,  0,  0>(vt, Pl, Ql, isPair, isCell, isVcol,
                          prow, qrow, i1, i2, s1f, Rv, lane, out, base);
    else              run_wave<3, 3, 64,  0, 3, 1, 64, 96>(vt, Pl, Ql, isPair, isCell, isVcol,
                          prow, qrow, i1, i2, s1f, Rv, lane, out, base);

    if (tid < 10) out[base + tid] = xb[2550 + tid] - xb[tid];   // S1 exact
}

extern "C" void kernel_launch(void* const* d_in, const int* in_sizes, int n_in,
                              void* d_out, int out_size, void* d_ws, size_t ws_size,
                              hipStream_t stream) {
    const float* x = (const float*)d_in[0];
    float* out = (float*)d_out;
    const int B = in_sizes[0] / 2560;   // 2048 batches, one block each
    sig_mfma15<<<B, 256, 0, stream>>>(x, out);
}

// Round 23
// 82.870 us; speedup vs baseline: 2.0532x; 1.0402x over previous
//
#include <hip/hip_runtime.h>

// Path signature M=4, d=10, L=256, B=2048 — MFMA formulation, round 23.
// Math identical to r17/r21/r22 (absmax 10.5): b-row eliminated; per-t K-rows:
// P=[a_hi,a_lo,r1,r2], Q_cell=[uw,uw,-w/24,-w/12], where a=r1/6+r2/2+S2,
// r1=vi*vj, r2=S1_i*vj, uw=vk*(R+v/2), w=vk*vl.
// ROUND-23: vcol rows (Q 100..109, the S3 columns) are produced by the SAME
// cell code path as a degenerate cell: i2 -> an all-zero 11th vt row, Rv=1.
// Then m2=1 (exact), uw=v (exact), w=0 -> word1=(-0.0,-0.0) which accumulates
// bit-identically to 0. This removes wave-1's cell/vcol divergence entirely.
// vt[dim][260] transposed increments (2x float4 ds_read per dim per chunk);
// s1f/Rv carried incrementally; vt[*][255]=0 kills the tail (32 uniform chunks).
// Partition 12/13/12/12 (max 52 acc regs), launch_bounds(256,4), dbuf,
// 1 barrier/chunk, slot-major [slot][112][16B].

#define SIG 11110

typedef short bf16x8 __attribute__((ext_vector_type(8)));
typedef float f32x4  __attribute__((ext_vector_type(4)));

__device__ __forceinline__ unsigned cvt_pk2(float lo, float hi) {
    unsigned r;
    asm("v_cvt_pk_bf16_f32 %0, %1, %2" : "=v"(r) : "v"(lo), "v"(hi));
    return r;
}
// (bf16_hi(a) | bf16(a - hi)<<16), hi = truncated-to-bf16 (exact residual)
__device__ __forceinline__ unsigned split_pack(float a) {
    const float hi = __uint_as_float(__float_as_uint(a) & 0xFFFF0000u);
    return cvt_pk2(hi, a - hi);
}

template<int MI, int NI>
__device__ __forceinline__ void consume(const unsigned* __restrict__ Pb,
                                        const unsigned* __restrict__ Qb,
                                        int r0, int c0, int lane,
                                        f32x4 (&acc)[MI][NI]) {
    const int slot = lane >> 4, rr = lane & 15;
    bf16x8 Bf[NI];
    #pragma unroll
    for (int ni = 0; ni < NI; ++ni)
        Bf[ni] = *(const bf16x8*)(Qb + slot * 448 + (c0 + ni * 16 + rr) * 4);
    #pragma unroll
    for (int mi = 0; mi < MI; ++mi) {
        const bf16x8 Af = *(const bf16x8*)(Pb + slot * 448 + (r0 + mi * 16 + rr) * 4);
        #pragma unroll
        for (int ni = 0; ni < NI; ++ni)
            acc[mi][ni] = __builtin_amdgcn_mfma_f32_16x16x32_bf16(Af, Bf[ni], acc[mi][ni], 0, 0, 0);
    }
}

template<int MI, int NI>
__device__ __forceinline__ void write_seg(int r0, int c0, int lane,
                                          const f32x4 (&acc)[MI][NI],
                                          float* __restrict__ out, size_t base) {
    #pragma unroll
    for (int mi = 0; mi < MI; ++mi) {
        #pragma unroll
        for (int ni = 0; ni < NI; ++ni) {
            #pragma unroll
            for (int r = 0; r < 4; ++r) {
                const int m = r0 + mi * 16 + (lane >> 4) * 4 + r;
                const int n = c0 + ni * 16 + (lane & 15);
                if (m < 100) {
                    if (n < 100)      out[base + 1110 + m * 100 + n]         = acc[mi][ni][r];
                    else if (n < 110) out[base + 110  + m * 10  + (n - 100)] = acc[mi][ni][r];
                }
            }
        }
    }
}

__device__ __forceinline__ void produce(int ch, const float* __restrict__ vt,
                                        unsigned* __restrict__ Pb,
                                        unsigned* __restrict__ Qb,
                                        bool isPair, bool isQ,
                                        int prow, int qrow, int i1, int i2,
                                        float& s1f, float& Rv, float& Ds) {
    if (isPair) {
        const float4 a0 = *(const float4*)(vt + i1 * 260 + ch * 8);
        const float4 a1 = *(const float4*)(vt + i1 * 260 + ch * 8 + 4);
        const float4 b0 = *(const float4*)(vt + i2 * 260 + ch * 8);
        const float4 b1 = *(const float4*)(vt + i2 * 260 + ch * 8 + 4);
        const float v1[8] = {a0.x,a0.y,a0.z,a0.w,a1.x,a1.y,a1.z,a1.w};
        const float v2[8] = {b0.x,b0.y,b0.z,b0.w,b1.x,b1.y,b1.z,b1.w};
        unsigned q0 = 0, q1 = 0;
        #pragma unroll
        for (int tl = 0; tl < 8; ++tl) {
            const float vi = v1[tl], vj = v2[tl];
            const float r1 = vi * vj;
            const float r2 = s1f * vj;
            const float a  = fmaf(r1, 1.f/6.f, fmaf(r2, 0.5f, Ds));
            const unsigned pa = split_pack(a), pr = cvt_pk2(r1, r2);
            Ds += fmaf(0.5f, r1, r2);
            s1f += vi;
            if ((tl & 1) == 0) { q0 = pa; q1 = pr; }
            else *(uint4*)&Pb[(tl >> 1) * 448 + prow * 4] = make_uint4(q0, q1, pa, pr);
        }
    } else if (isQ) {     // cells 0..99 AND vcols 100..109 (i2 = zero row, Rv=1)
        const float4 a0 = *(const float4*)(vt + i1 * 260 + ch * 8);
        const float4 a1 = *(const float4*)(vt + i1 * 260 + ch * 8 + 4);
        const float4 b0 = *(const float4*)(vt + i2 * 260 + ch * 8);
        const float4 b1 = *(const float4*)(vt + i2 * 260 + ch * 8 + 4);
        const float v1[8] = {a0.x,a0.y,a0.z,a0.w,a1.x,a1.y,a1.z,a1.w};
        const float v2[8] = {b0.x,b0.y,b0.z,b0.w,b1.x,b1.y,b1.z,b1.w};
        unsigned q0 = 0, q1 = 0;
        #pragma unroll
        for (int tl = 0; tl < 8; ++tl) {
            const float vk = v1[tl], vl = v2[tl];
            const float w  = vk * vl;
            const float m2 = fmaf(-0.5f, vl, Rv);   // cells: xL-(x_t+x_{t+1})/2 ; vcols: 1
            Rv -= vl;
            const float uw = vk * m2;               // cells: u+w/2 ; vcols: v (exact)
            const unsigned pu = cvt_pk2(uw, uw);
            const unsigned pw = cvt_pk2(w * (-1.f/24.f), w * (-1.f/12.f));
            if ((tl & 1) == 0) { q0 = pu; q1 = pw; }
            else *(uint4*)&Qb[(tl >> 1) * 448 + qrow * 4] = make_uint4(q0, q1, pu, pw);
        }
    }
}

// Whole chunk-loop per wave: exactly-sized accumulators. B segment optional (MIB=0).
template<int MIA, int NIA, int R0A, int C0A, int MIB, int NIB, int R0B, int C0B>
__device__ __forceinline__ void run_wave(const float* __restrict__ vt,
                                         unsigned (&Pl)[2][1792],
                                         unsigned (&Ql)[2][1792],
                                         bool isPair, bool isQ,
                                         int prow, int qrow, int i1, int i2,
                                         float s1f, float Rv,
                                         int lane, float* __restrict__ out, size_t base) {
    float Ds = 0.f;
    f32x4 accA[MIA][NIA];
    #pragma unroll
    for (int mi = 0; mi < MIA; ++mi)
        #pragma unroll
        for (int ni = 0; ni < NIA; ++ni) accA[mi][ni] = (f32x4){0.f, 0.f, 0.f, 0.f};
    constexpr int MB = (MIB > 0) ? MIB : 1;
    constexpr int NB = (NIB > 0) ? NIB : 1;
    f32x4 accB[MB][NB];
    if constexpr (MIB > 0) {
        #pragma unroll
        for (int mi = 0; mi < MB; ++mi)
            #pragma unroll
            for (int ni = 0; ni < NB; ++ni) accB[mi][ni] = (f32x4){0.f, 0.f, 0.f, 0.f};
    }

    produce(0, vt, Pl[0], Ql[0], isPair, isQ, prow, qrow, i1, i2, s1f, Rv, Ds);
    __syncthreads();

    for (int ch = 0; ch < 32; ++ch) {
        const unsigned* Pb = Pl[ch & 1];
        const unsigned* Qb = Ql[ch & 1];
        consume<MIA, NIA>(Pb, Qb, R0A, C0A, lane, accA);
        if constexpr (MIB > 0) consume<MIB, NIB>(Pb, Qb, R0B, C0B, lane, accB);
        if (ch < 31)
            produce(ch + 1, vt, Pl[(ch + 1) & 1], Ql[(ch + 1) & 1],
                    isPair, isQ, prow, qrow, i1, i2, s1f, Rv, Ds);
        __syncthreads();   // 33 barriers in every instantiation — counts match
    }

    if (isPair) out[base + 10 + prow] = Ds;          // S2 exact
    write_seg<MIA, NIA>(R0A, C0A, lane, accA, out, base);
    if constexpr (MIB > 0) write_seg<MIB, NIB>(R0B, C0B, lane, accB, out, base);
}

__global__ __launch_bounds__(256, 4)
void sig_mfma16(const float* __restrict__ xg, float* __restrict__ out) {
    __shared__ float    vt[11 * 260];      // increments [dim][260]; row 10 = zeros
    __shared__ unsigned Pl[2][1792];       // dbuf [slot][112 rows][4w] 14336 B
    __shared__ unsigned Ql[2][1792];       //                           14336 B

    const int tid  = threadIdx.x;
    const int b    = blockIdx.x;
    const int lane = tid & 63;
    const int wv   = tid >> 6;
    const float* __restrict__ xb = xg + (size_t)b * 2560;

    // stage increments transposed (coalesced global reads, L1 absorbs the x2)
    for (int e = tid; e < 2550; e += 256) {
        const int t = e / 10, d = e - t * 10;
        vt[d * 260 + t] = xb[e + 10] - xb[e];
    }
    if (tid < 10) vt[tid * 260 + 255] = 0.f;    // t=255 contributes exactly 0
    for (int e = tid; e < 260; e += 256) vt[10 * 260 + e] = 0.f;   // zero dim row
    // zero pads: P rows 100..111, Q rows 110..111 (both bufs)
    for (int e = tid; e < 384; e += 256) {
        const int buf = e / 192, r = e % 192, slot = r / 48, rem = r % 48;
        Pl[buf][slot * 448 + (100 + rem / 4) * 4 + (rem & 3)] = 0u;
    }
    if (tid < 64) {
        const int buf = tid / 32, r = tid % 32, slot = r / 8, rem = r % 8;
        Ql[buf][slot * 448 + (110 + rem / 4) * 4 + (rem & 3)] = 0u;
    }
    __syncthreads();   // staging visible BEFORE produce(0) (r12/r13 lesson)

    // roles: waves 0-1 = Q rows (cells 0..99, vcols-as-cells 100..109);
    //        waves 2-3 = pair scan -> P
    const int  pid    = tid - 128;
    const bool isPair = (pid >= 0) && (pid < 100);
    const bool isQ    = (tid < 110);
    const int  prow   = isPair ? pid : 0;
    const int  qrow   = tid;

    int i1 = 0, i2 = 0;
    if (isPair)          { i1 = pid / 10; i2 = pid - i1 * 10; }
    else if (tid < 100)  { i1 = tid / 10; i2 = tid - i1 * 10; }   // cell
    else if (tid < 110)  { i1 = tid - 100; i2 = 10; }             // vcol: zero row

    const float s1f = 0.f;
    float Rv = 0.f;
    if (tid < 100)      Rv = xb[2550 + i2] - xb[i2];   // cell: xL - x0
    else if (tid < 110) Rv = 1.f;                      // vcol: m2 == 1 forever
    const size_t base = (size_t)b * SIG;

    // tile partition 12/13/12/12 (max 52 acc regs); Q waves take the 13:
    if      (wv == 0) run_wave<4, 3,  0, 48, 0, 0,  0,  0>(vt, Pl, Ql, isPair, isQ,
                          prow, qrow, i1, i2, s1f, Rv, lane, out, base);
    else if (wv == 1) run_wave<3, 3, 64, 48, 4, 1,  0, 96>(vt, Pl, Ql, isPair, isQ,
                          prow, qrow, i1, i2, s1f, Rv, lane, out, base);
    else if (wv == 2) run_wave<4, 3,  0,  0, 0, 0,  0,  0>(vt, Pl, Ql, isPair, isQ,
                          prow, qrow, i1, i2, s1f, Rv, lane, out, base);
    else              run_wave<3, 3, 64,  0, 3, 1, 64, 96>(vt, Pl, Ql, isPair, isQ,
                          prow, qrow, i1, i2, s1f, Rv, lane, out, base);

    if (tid < 10) out[base + tid] = xb[2550 + tid] - xb[tid];   // S1 exact
}

extern "C" void kernel_launch(void* const* d_in, const int* in_sizes, int n_in,
                              void* d_out, int out_size, void* d_ws, size_t ws_size,
                              hipStream_t stream) {
    const float* x = (const float*)d_in[0];
    float* out = (float*)d_out;
    const int B = in_sizes[0] / 2560;   // 2048 batches, one block each
    sig_mfma16<<<B, 256, 0, stream>>>(x, out);
}

// Round 24
// 76.338 us; speedup vs baseline: 2.2288x; 1.0856x over previous
//
#include <hip/hip_runtime.h>

// Path signature M=4, d=10, L=256, B=2048 — MFMA formulation, round 24.
// Algebra (r17 lineage, absmax 10.5): per t,
//   S4 += a·(u+w/2) + r1·(-w/24) + r2·(-w/12);  S3 via vcol-as-degenerate-cell.
// ROUND-24: merge the two correction rows: r1·(-w/24)+r2·(-w/12) = r12·(-w/24),
// r12 = r1+2·r2 (fp32, rounded once — same weighting, same error order).
// K-rows per t: P=[a_hi,a_lo,r12], Q=[uw,uw,-w/24]  ->  K = 3·256 = 768 (was 1024).
// 10 t's per K=32 chunk (30 slots + 2 zero-pad) -> 26 chunks, 27 barriers (was 33);
// MFMA count and consume frag-reads -19%. vt t-rows 255..259 zeroed -> those t's
// contribute exactly 0 via zero Q entries (P holds a=Ds there; product still 0).
// vt[dim][260] transposed (5x float2 per dim per chunk, 8B-aligned at t=10·ch).
// Partition 12/13/12/12 (max 52 acc), launch_bounds(256,4), dbuf, slot-major.

#define SIG 11110
#define NCH 26

typedef short bf16x8 __attribute__((ext_vector_type(8)));
typedef float f32x4  __attribute__((ext_vector_type(4)));

__device__ __forceinline__ unsigned cvt_pk2(float lo, float hi) {
    unsigned r;
    asm("v_cvt_pk_bf16_f32 %0, %1, %2" : "=v"(r) : "v"(lo), "v"(hi));
    return r;
}

template<int MI, int NI>
__device__ __forceinline__ void consume(const unsigned* __restrict__ Pb,
                                        const unsigned* __restrict__ Qb,
                                        int r0, int c0, int lane,
                                        f32x4 (&acc)[MI][NI]) {
    const int slot = lane >> 4, rr = lane & 15;
    bf16x8 Bf[NI];
    #pragma unroll
    for (int ni = 0; ni < NI; ++ni)
        Bf[ni] = *(const bf16x8*)(Qb + slot * 448 + (c0 + ni * 16 + rr) * 4);
    #pragma unroll
    for (int mi = 0; mi < MI; ++mi) {
        const bf16x8 Af = *(const bf16x8*)(Pb + slot * 448 + (r0 + mi * 16 + rr) * 4);
        #pragma unroll
        for (int ni = 0; ni < NI; ++ni)
            acc[mi][ni] = __builtin_amdgcn_mfma_f32_16x16x32_bf16(Af, Bf[ni], acc[mi][ni], 0, 0, 0);
    }
}

template<int MI, int NI>
__device__ __forceinline__ void write_seg(int r0, int c0, int lane,
                                          const f32x4 (&acc)[MI][NI],
                                          float* __restrict__ out, size_t base) {
    #pragma unroll
    for (int mi = 0; mi < MI; ++mi) {
        #pragma unroll
        for (int ni = 0; ni < NI; ++ni) {
            #pragma unroll
            for (int r = 0; r < 4; ++r) {
                const int m = r0 + mi * 16 + (lane >> 4) * 4 + r;
                const int n = c0 + ni * 16 + (lane & 15);
                if (m < 100) {
                    if (n < 100)      out[base + 1110 + m * 100 + n]         = acc[mi][ni][r];
                    else if (n < 110) out[base + 110  + m * 10  + (n - 100)] = acc[mi][ni][r];
                }
            }
        }
    }
}

__device__ __forceinline__ void produce(int ch, const float* __restrict__ vt,
                                        unsigned* __restrict__ Pb,
                                        unsigned* __restrict__ Qb,
                                        bool isPair, bool isQ,
                                        int prow, int qrow, int i1, int i2,
                                        float& s1f, float& Rv, float& Ds) {
    float v1[10], v2[10];
    {
        const float* p1 = vt + i1 * 260 + ch * 10;
        const float* p2 = vt + i2 * 260 + ch * 10;
        #pragma unroll
        for (int k = 0; k < 5; ++k) {
            const float2 x = *(const float2*)(p1 + 2 * k);
            const float2 y = *(const float2*)(p2 + 2 * k);
            v1[2 * k] = x.x; v1[2 * k + 1] = x.y;
            v2[2 * k] = y.x; v2[2 * k + 1] = y.y;
        }
    }
    if (isPair) {
        float ah[10], al[10], rr[10];
        #pragma unroll
        for (int tl = 0; tl < 10; ++tl) {
            const float vi = v1[tl], vj = v2[tl];
            const float r1 = vi * vj;
            const float r2 = s1f * vj;
            const float a  = fmaf(r1, 1.f/6.f, fmaf(r2, 0.5f, Ds));
            const float hi = __uint_as_float(__float_as_uint(a) & 0xFFFF0000u);
            ah[tl] = hi; al[tl] = a - hi;          // exact residual
            rr[tl] = fmaf(2.f, r2, r1);            // r12 = r1 + 2·r2
            Ds += fmaf(0.5f, r1, r2);
            s1f += vi;
        }
        unsigned wd[15];
        #pragma unroll
        for (int m = 0; m < 5; ++m) {
            wd[3 * m + 0] = cvt_pk2(ah[2 * m],     al[2 * m]);
            wd[3 * m + 1] = cvt_pk2(rr[2 * m],     ah[2 * m + 1]);
            wd[3 * m + 2] = cvt_pk2(al[2 * m + 1], rr[2 * m + 1]);
        }
        *(uint4*)&Pb[0 * 448 + prow * 4] = make_uint4(wd[0],  wd[1],  wd[2],  wd[3]);
        *(uint4*)&Pb[1 * 448 + prow * 4] = make_uint4(wd[4],  wd[5],  wd[6],  wd[7]);
        *(uint4*)&Pb[2 * 448 + prow * 4] = make_uint4(wd[8],  wd[9],  wd[10], wd[11]);
        *(uint4*)&Pb[3 * 448 + prow * 4] = make_uint4(wd[12], wd[13], wd[14], 0u);
    } else if (isQ) {       // cells 0..99 AND vcols 100..109 (i2=zero row, Rv=1)
        float uw[10], mw[10];
        #pragma unroll
        for (int tl = 0; tl < 10; ++tl) {
            const float vk = v1[tl], vl = v2[tl];
            const float w  = vk * vl;
            const float m2 = fmaf(-0.5f, vl, Rv);  // cells: xL-(x_t+x_{t+1})/2; vcol: 1
            Rv -= vl;
            uw[tl] = vk * m2;                      // cells: u+w/2 ; vcol: v (exact)
            mw[tl] = w * (-1.f/24.f);
        }
        unsigned wd[15];
        #pragma unroll
        for (int m = 0; m < 5; ++m) {
            wd[3 * m + 0] = cvt_pk2(uw[2 * m],     uw[2 * m]);
            wd[3 * m + 1] = cvt_pk2(mw[2 * m],     uw[2 * m + 1]);
            wd[3 * m + 2] = cvt_pk2(uw[2 * m + 1], mw[2 * m + 1]);
        }
        *(uint4*)&Qb[0 * 448 + qrow * 4] = make_uint4(wd[0],  wd[1],  wd[2],  wd[3]);
        *(uint4*)&Qb[1 * 448 + qrow * 4] = make_uint4(wd[4],  wd[5],  wd[6],  wd[7]);
        *(uint4*)&Qb[2 * 448 + qrow * 4] = make_uint4(wd[8],  wd[9],  wd[10], wd[11]);
        *(uint4*)&Qb[3 * 448 + qrow * 4] = make_uint4(wd[12], wd[13], wd[14], 0u);
    }
}

// Whole chunk-loop per wave: exactly-sized accumulators. B segment optional (MIB=0).
template<int MIA, int NIA, int R0A, int C0A, int MIB, int NIB, int R0B, int C0B>
__device__ __forceinline__ void run_wave(const float* __restrict__ vt,
                                         unsigned (&Pl)[2][1792],
                                         unsigned (&Ql)[2][1792],
                                         bool isPair, bool isQ,
                                         int prow, int qrow, int i1, int i2,
                                         float s1f, float Rv,
                                         int lane, float* __restrict__ out, size_t base) {
    float Ds = 0.f;
    f32x4 accA[MIA][NIA];
    #pragma unroll
    for (int mi = 0; mi < MIA; ++mi)
        #pragma unroll
        for (int ni = 0; ni < NIA; ++ni) accA[mi][ni] = (f32x4){0.f, 0.f, 0.f, 0.f};
    constexpr int MB = (MIB > 0) ? MIB : 1;
    constexpr int NB = (NIB > 0) ? NIB : 1;
    f32x4 accB[MB][NB];
    if constexpr (MIB > 0) {
        #pragma unroll
        for (int mi = 0; mi < MB; ++mi)
            #pragma unroll
            for (int ni = 0; ni < NB; ++ni) accB[mi][ni] = (f32x4){0.f, 0.f, 0.f, 0.f};
    }

    produce(0, vt, Pl[0], Ql[0], isPair, isQ, prow, qrow, i1, i2, s1f, Rv, Ds);
    __syncthreads();

    for (int ch = 0; ch < NCH; ++ch) {
        const unsigned* Pb = Pl[ch & 1];
        const unsigned* Qb = Ql[ch & 1];
        consume<MIA, NIA>(Pb, Qb, R0A, C0A, lane, accA);
        if constexpr (MIB > 0) consume<MIB, NIB>(Pb, Qb, R0B, C0B, lane, accB);
        if (ch < NCH - 1)
            produce(ch + 1, vt, Pl[(ch + 1) & 1], Ql[(ch + 1) & 1],
                    isPair, isQ, prow, qrow, i1, i2, s1f, Rv, Ds);
        __syncthreads();   // 27 barriers in every instantiation — counts match
    }

    if (isPair) out[base + 10 + prow] = Ds;          // S2 exact
    write_seg<MIA, NIA>(R0A, C0A, lane, accA, out, base);
    if constexpr (MIB > 0) write_seg<MIB, NIB>(R0B, C0B, lane, accB, out, base);
}

__global__ __launch_bounds__(256, 4)
void sig_mfma17(const float* __restrict__ xg, float* __restrict__ out) {
    __shared__ float    vt[11 * 260];      // increments [dim][260]; row 10 = zeros
    __shared__ unsigned Pl[2][1792];       // dbuf [slot][112 rows][4w] 14336 B
    __shared__ unsigned Ql[2][1792];       //                           14336 B

    const int tid  = threadIdx.x;
    const int b    = blockIdx.x;
    const int lane = tid & 63;
    const int wv   = tid >> 6;
    const float* __restrict__ xb = xg + (size_t)b * 2560;

    // stage increments transposed (coalesced global reads; L1 absorbs the x2)
    for (int e = tid; e < 2550; e += 256) {
        const int t = e / 10, d = e - t * 10;
        vt[d * 260 + t] = xb[e + 10] - xb[e];
    }
    if (tid < 55) vt[(tid / 5) * 260 + 255 + (tid % 5)] = 0.f;  // t 255..259 = 0
    for (int e = tid; e < 260; e += 256) vt[10 * 260 + e] = 0.f; // zero dim row
    // zero pads: P rows 100..111, Q rows 110..111 (both bufs)
    for (int e = tid; e < 384; e += 256) {
        const int buf = e / 192, r = e % 192, slot = r / 48, rem = r % 48;
        Pl[buf][slot * 448 + (100 + rem / 4) * 4 + (rem & 3)] = 0u;
    }
    if (tid < 64) {
        const int buf = tid / 32, r = tid % 32, slot = r / 8, rem = r % 8;
        Ql[buf][slot * 448 + (110 + rem / 4) * 4 + (rem & 3)] = 0u;
    }
    __syncthreads();   // staging visible BEFORE produce(0) (r12/r13 lesson)

    // roles: waves 0-1 = Q rows (cells 0..99, vcols-as-cells 100..109);
    //        waves 2-3 = pair scan -> P
    const int  pid    = tid - 128;
    const bool isPair = (pid >= 0) && (pid < 100);
    const bool isQ    = (tid < 110);
    const int  prow   = isPair ? pid : 0;
    const int  qrow   = tid;

    int i1 = 0, i2 = 0;
    if (isPair)          { i1 = pid / 10; i2 = pid - i1 * 10; }
    else if (tid < 100)  { i1 = tid / 10; i2 = tid - i1 * 10; }   // cell
    else if (tid < 110)  { i1 = tid - 100; i2 = 10; }             // vcol: zero row

    const float s1f = 0.f;
    float Rv = 0.f;
    if (tid < 100)      Rv = xb[2550 + i2] - xb[i2];   // cell: xL - x0
    else if (tid < 110) Rv = 1.f;                      // vcol: m2 == 1 forever
    const size_t base = (size_t)b * SIG;

    // tile partition 12/13/12/12 (max 52 acc regs); Q waves take the 13:
    if      (wv == 0) run_wave<4, 3,  0, 48, 0, 0,  0,  0>(vt, Pl, Ql, isPair, isQ,
                          prow, qrow, i1, i2, s1f, Rv, lane, out, base);
    else if (wv == 1) run_wave<3, 3, 64, 48, 4, 1,  0, 96>(vt, Pl, Ql, isPair, isQ,
                          prow, qrow, i1, i2, s1f, Rv, lane, out, base);
    else if (wv == 2) run_wave<4, 3,  0,  0, 0, 0,  0,  0>(vt, Pl, Ql, isPair, isQ,
                          prow, qrow, i1, i2, s1f, Rv, lane, out, base);
    else              run_wave<3, 3, 64,  0, 3, 1, 64, 96>(vt, Pl, Ql, isPair, isQ,
                          prow, qrow, i1, i2, s1f, Rv, lane, out, base);

    if (tid < 10) out[base + tid] = xb[2550 + tid] - xb[tid];   // S1 exact
}

extern "C" void kernel_launch(void* const* d_in, const int* in_sizes, int n_in,
                              void* d_out, int out_size, void* d_ws, size_t ws_size,
                              hipStream_t stream) {
    const float* x = (const float*)d_in[0];
    float* out = (float*)d_out;
    const int B = in_sizes[0] / 2560;   // 2048 batches, one block each
    sig_mfma17<<<B, 256, 0, stream>>>(x, out);
}